// Round 2
// baseline (1358.174 us; speedup 1.0000x reference)
//
#include <hip/hip_runtime.h>

#define TT   512
#define HD   18
#define CH   8              /* batches per block */
#define UNITS (CH*HD)       /* 144 active lanes per role */
#define R1BASE 192          /* role-2 threads start at wave 3 */
#define NTH  384
#define ROWF 40             /* 36 floats + 4 pad; 160B rows, 16B aligned */

__device__ __forceinline__ float fsig(float x) {
    return __builtin_amdgcn_rcpf(1.0f + __expf(-x));
}
__device__ __forceinline__ float ftanh(float x) {
    return 2.0f * __builtin_amdgcn_rcpf(1.0f + __expf(-2.0f * x)) - 1.0f;
}

__global__ __launch_bounds__(NTH, 3) void lstm2_pipe(
    const float* __restrict__ x,
    const float* __restrict__ wih0, const float* __restrict__ whh0,
    const float* __restrict__ bih0, const float* __restrict__ bhh0,
    const float* __restrict__ wih1, const float* __restrict__ whh1,
    const float* __restrict__ bih1, const float* __restrict__ bhh1,
    float* __restrict__ out)
{
    // double-buffered input rows: layer1 row = [x(18) | h1(18) | pad4]
    //                             layer2 row = [h1(18) | h2(18) | pad4]
    __shared__ __align__(16) float in1[2][CH][ROWF];
    __shared__ __align__(16) float in2[2][CH][ROWF];

    const int  tid   = threadIdx.x;
    const bool role2 = (tid >= R1BASE);           // wave-uniform
    const int  unit  = role2 ? (tid - R1BASE) : tid;
    const bool act   = (unit < UNITS);
    const int  bl    = unit / HD;
    const int  h     = unit % HD;
    const int  b     = blockIdx.x * CH + bl;

    // ---- per-lane weights for ONE layer: 4 combined gate rows [wih|whh] ----
    float4 W[4][9];
    float  bias[4];
    if (act) {
        const float* wih = role2 ? wih1 : wih0;
        const float* whh = role2 ? whh1 : whh0;
        const float* bi  = role2 ? bih1 : bih0;
        const float* bh  = role2 ? bhh1 : bhh0;
        #pragma unroll
        for (int g = 0; g < 4; ++g) {
            const int r = g * HD + h;
            float wr[36];
            #pragma unroll
            for (int k = 0; k < HD; ++k) {
                wr[k]      = wih[r * HD + k];
                wr[HD + k] = whh[r * HD + k];
            }
            #pragma unroll
            for (int j = 0; j < 9; ++j)
                W[g][j] = make_float4(wr[4*j], wr[4*j+1], wr[4*j+2], wr[4*j+3]);
            bias[g] = bi[r] + bh[r];
        }
    }

    // ---- init LDS: zero h1[-1] and h2[-1] slots; preload x[0] ----
    for (int i = tid; i < UNITS; i += NTH) {
        const int bb = i / HD, hh = i % HD;
        in1[0][bb][HD + hh] = 0.0f;   // h1[-1]
        in2[1][bb][HD + hh] = 0.0f;   // h2[-1] (read at n=1 from buffer 1)
    }
    const float* xrow = x   + ((size_t)b * TT) * HD + h;
    float*       orow = out + ((size_t)b * TT) * HD + h;
    if (!role2 && act) in1[0][bl][h] = xrow[0];
    __syncthreads();

    float c = 0.0f;

    for (int n = 0; n <= TT; ++n) {
        const int p = n & 1;
        if (!role2) {
            // ---- layer 1: compute h1[n] from (x[n], h1[n-1]) ----
            if (n < TT && act) {
                const float xn = (n + 1 < TT) ? xrow[(size_t)(n + 1) * HD] : 0.0f;
                const float4* rp = (const float4*)&in1[p][bl][0];
                float a0 = bias[0], a1 = bias[1], a2 = bias[2], a3 = bias[3];
                #pragma unroll
                for (int j = 0; j < 9; ++j) {
                    const float4 v = rp[j];
                    a0 += W[0][j].x * v.x + W[0][j].y * v.y + W[0][j].z * v.z + W[0][j].w * v.w;
                    a1 += W[1][j].x * v.x + W[1][j].y * v.y + W[1][j].z * v.z + W[1][j].w * v.w;
                    a2 += W[2][j].x * v.x + W[2][j].y * v.y + W[2][j].z * v.z + W[2][j].w * v.w;
                    a3 += W[3][j].x * v.x + W[3][j].y * v.y + W[3][j].z * v.z + W[3][j].w * v.w;
                }
                const float ig = fsig(a0), fg = fsig(a1), gg = ftanh(a2), og = fsig(a3);
                c = fg * c + ig * gg;
                const float hv = og * ftanh(c);
                in1[p ^ 1][bl][HD + h] = hv;   // h1 for layer-1 @ n+1
                in2[p ^ 1][bl][h]      = hv;   // h1 for layer-2 @ n+1
                in1[p ^ 1][bl][h]      = xn;   // x for layer-1 @ n+1
            }
        } else {
            // ---- layer 2: compute h2[n-1] from (h1[n-1], h2[n-2]) ----
            if (n >= 1 && act) {
                const float4* rp = (const float4*)&in2[p][bl][0];
                float a0 = bias[0], a1 = bias[1], a2 = bias[2], a3 = bias[3];
                #pragma unroll
                for (int j = 0; j < 9; ++j) {
                    const float4 v = rp[j];
                    a0 += W[0][j].x * v.x + W[0][j].y * v.y + W[0][j].z * v.z + W[0][j].w * v.w;
                    a1 += W[1][j].x * v.x + W[1][j].y * v.y + W[1][j].z * v.z + W[1][j].w * v.w;
                    a2 += W[2][j].x * v.x + W[2][j].y * v.y + W[2][j].z * v.z + W[2][j].w * v.w;
                    a3 += W[3][j].x * v.x + W[3][j].y * v.y + W[3][j].z * v.z + W[3][j].w * v.w;
                }
                const float ig = fsig(a0), fg = fsig(a1), gg = ftanh(a2), og = fsig(a3);
                c = fg * c + ig * gg;
                const float hv = og * ftanh(c);
                in2[p ^ 1][bl][HD + h] = hv;           // h2 for layer-2 @ n+1
                orow[(size_t)(n - 1) * HD] = hv;       // final output
            }
        }
        __syncthreads();
    }
}

extern "C" void kernel_launch(void* const* d_in, const int* in_sizes, int n_in,
                              void* d_out, int out_size, void* d_ws, size_t ws_size,
                              hipStream_t stream) {
    const float* x    = (const float*)d_in[0];
    const float* wih0 = (const float*)d_in[1];
    const float* whh0 = (const float*)d_in[2];
    const float* bih0 = (const float*)d_in[3];
    const float* bhh0 = (const float*)d_in[4];
    const float* wih1 = (const float*)d_in[5];
    const float* whh1 = (const float*)d_in[6];
    const float* bih1 = (const float*)d_in[7];
    const float* bhh1 = (const float*)d_in[8];
    float* out = (float*)d_out;

    lstm2_pipe<<<dim3(4096 / CH), dim3(NTH), 0, stream>>>(
        x, wih0, whh0, bih0, bhh0, wih1, whh1, bih1, bhh1, out);
}

// Round 3
// 732.679 us; speedup vs baseline: 1.8537x; 1.8537x over previous
//
#include <hip/hip_runtime.h>

#define TT   512
#define HD   18
#define CH   8                 /* batches per block */
#define UPR  (CH*HD*2)         /* 288 active units per role (b,h,gate-pair) */
#define SLOT 320               /* role slot padded to 5 waves */
#define NTH  (2*SLOT)          /* 640 threads = 10 waves */
#define ROWF 40                /* 36 floats + pad, 160B rows */

typedef float v2f __attribute__((ext_vector_type(2)));

__device__ __forceinline__ v2f mk2(float a, float b){ v2f r; r.x=a; r.y=b; return r; }
__device__ __forceinline__ float fsig(float x){ return __builtin_amdgcn_rcpf(1.0f + __expf(-x)); }

__global__ __launch_bounds__(NTH, 5) void lstm2_gp(
    const float* __restrict__ x,
    const float* __restrict__ wih0, const float* __restrict__ whh0,
    const float* __restrict__ bih0, const float* __restrict__ bhh0,
    const float* __restrict__ wih1, const float* __restrict__ whh1,
    const float* __restrict__ bih1, const float* __restrict__ bhh1,
    float* __restrict__ out)
{
    // layer-1 input rows: [x(18) | h1(18) | pad4]; layer-2: [h1(18) | h2(18) | pad4]
    __shared__ __align__(16) float in1[2][CH][ROWF];
    __shared__ __align__(16) float in2[2][CH][ROWF];

    const int  tid   = threadIdx.x;
    const bool role2 = (tid >= SLOT);              // wave-uniform (5 waves per role)
    const int  u     = role2 ? tid - SLOT : tid;
    const bool act   = (u < UPR);
    const int  b     = u / 36;
    const int  r     = u % 36;
    const int  h     = r >> 1;
    const int  gp    = r & 1;                      // 0: gates (i,f); 1: gates (g,o)
    const size_t gb  = (size_t)blockIdx.x * CH + b;

    // ---- per-lane weights: TWO gate rows, packed as v2f -> 72 VGPRs ----
    v2f Wp[36];
    v2f bias = mk2(0.f, 0.f);
    if (act) {
        const float* wih = role2 ? wih1 : wih0;
        const float* whh = role2 ? whh1 : whh0;
        const float* bi  = role2 ? bih1 : bih0;
        const float* bh  = role2 ? bhh1 : bhh0;
        const int r0 = (gp ? 2*HD : 0) + h;        // i-row or g-row
        const int r1 = (gp ? 3*HD : HD) + h;       // f-row or o-row (both sigmoid)
        #pragma unroll
        for (int k = 0; k < HD; ++k) {
            Wp[k]      = mk2(wih[r0*HD + k], wih[r1*HD + k]);
            Wp[HD + k] = mk2(whh[r0*HD + k], whh[r1*HD + k]);
        }
        bias = mk2(bi[r0] + bh[r0], bi[r1] + bh[r1]);
    }

    // ---- init LDS state ----
    if (act) {
        if (!role2) {
            if (gp) in1[0][b][h]      = x[gb*TT*HD + h];  // x[b][0][:]
            else    in1[0][b][HD + h] = 0.f;              // h1[-1]
        } else if (!gp) {
            in2[1][b][HD + h] = 0.f;                      // h2[-1], read at n=1
        }
    }
    __syncthreads();

    float c = 0.f;
    const float* xb = x   + gb*TT*HD;
    float*       ob = out + gb*TT*HD;

    for (int n = 0; n <= TT; ++n) {
        const int  p   = n & 1;
        const bool run = act && (role2 ? (n >= 1) : (n < TT));

        // prefetch next x element (layer-1, gp1 lanes stage x)
        float xn = 0.f;
        if (!role2 && act && gp && (n + 1) < TT) xn = xb[(size_t)(n + 1)*HD + h];

        if (run) {
            const float4* rp = (const float4*)(role2 ? &in2[p][b][0] : &in1[p][b][0]);
            v2f acc = bias;
            #pragma unroll
            for (int j = 0; j < 9; ++j) {
                const float4 v = rp[j];
                acc += Wp[4*j+0] * mk2(v.x, v.x);
                acc += Wp[4*j+1] * mk2(v.y, v.y);
                acc += Wp[4*j+2] * mk2(v.z, v.z);
                acc += Wp[4*j+3] * mk2(v.w, v.w);
            }
            const float a0 = acc.x, a1 = acc.y;
            // slot0: i (sigmoid) for gp0, g (tanh via 2*sig(2x)-1) for gp1
            const float s0 = fsig(gp ? 2.f*a0 : a0);
            const float g0 = gp ? 2.f*s0 - 1.f : s0;
            const float g1 = fsig(a1);                 // f (gp0) or o (gp1)
            const float gg = __shfl_xor(g0, 1, 64);    // gp0 receives g
            const float oo = __shfl_xor(g1, 1, 64);    // gp0 receives o
            if (!gp) {
                c = g1 * c + g0 * gg;                  // c = f*c + i*g
                const float th = 2.f * fsig(2.f*c) - 1.f;
                const float hv = oo * th;
                if (!role2) {
                    in1[p^1][b][HD + h] = hv;          // h1 -> layer-1 next input
                    in2[p^1][b][h]      = hv;          // h1 -> layer-2 next input
                } else {
                    in2[p^1][b][HD + h] = hv;          // h2 -> layer-2 next input
                    ob[(size_t)(n - 1)*HD + h] = hv;   // final output h2[n-1]
                }
            } else if (!role2 && (n + 1) < TT) {
                in1[p^1][b][h] = xn;                   // stage x[n+1]
            }
        }
        __syncthreads();
    }
}

extern "C" void kernel_launch(void* const* d_in, const int* in_sizes, int n_in,
                              void* d_out, int out_size, void* d_ws, size_t ws_size,
                              hipStream_t stream) {
    const float* x    = (const float*)d_in[0];
    const float* wih0 = (const float*)d_in[1];
    const float* whh0 = (const float*)d_in[2];
    const float* bih0 = (const float*)d_in[3];
    const float* bhh0 = (const float*)d_in[4];
    const float* wih1 = (const float*)d_in[5];
    const float* whh1 = (const float*)d_in[6];
    const float* bih1 = (const float*)d_in[7];
    const float* bhh1 = (const float*)d_in[8];
    float* out = (float*)d_out;

    lstm2_gp<<<dim3(4096 / CH), dim3(NTH), 0, stream>>>(
        x, wih0, whh0, bih0, bhh0, wih1, whh1, bih1, bhh1, out);
}

// Round 4
// 553.296 us; speedup vs baseline: 2.4547x; 1.3242x over previous
//
#include <hip/hip_runtime.h>

#define TT   512
#define HD   18
#define CH   8                 /* batches per block */
#define UPR  (CH*HD*2)         /* 288 active units per role */
#define SLOT 320               /* role slot = 5 waves */
#define NTH  (2*SLOT)          /* 640 threads */
#define ROWU 20                /* uints per LDS row: 18 data + 2 pad (80B) */

typedef _Float16 v2h __attribute__((ext_vector_type(2)));

__device__ __forceinline__ float fsig(float x){ return __builtin_amdgcn_rcpf(1.0f + __expf(-x)); }

__global__ __launch_bounds__(NTH, 5) void lstm2_dot(
    const float* __restrict__ x,
    const float* __restrict__ wih0, const float* __restrict__ whh0,
    const float* __restrict__ bih0, const float* __restrict__ bhh0,
    const float* __restrict__ wih1, const float* __restrict__ whh1,
    const float* __restrict__ bih1, const float* __restrict__ bhh1,
    float* __restrict__ out)
{
    // f16 rows, viewed as uint pairs. layer1 row: f16[0..17]=x, [18..35]=h1.
    // layer2 row: f16[0..17]=h1, [18..35]=h2.
    __shared__ uint in1[2][CH][ROWU];
    __shared__ uint in2[2][CH][ROWU];

    const int  tid   = threadIdx.x;
    const bool role2 = (tid >= SLOT);              // wave-uniform
    const int  u     = role2 ? tid - SLOT : tid;
    const bool act   = (u < UPR);
    const int  b     = u / 36;
    const int  r     = u % 36;
    const int  h     = r >> 1;
    const int  gp    = r & 1;                      // 0:(i,f)  1:(g,o)
    const size_t gb  = (size_t)blockIdx.x * CH + b;

    // ---- per-lane f16 weights for TWO gate rows: 36 VGPRs total ----
    v2h W0[18], W1[18];
    float bias0 = 0.f, bias1 = 0.f;
    if (act) {
        const float* wih = role2 ? wih1 : wih0;
        const float* whh = role2 ? whh1 : whh0;
        const float* bi  = role2 ? bih1 : bih0;
        const float* bh  = role2 ? bhh1 : bhh0;
        const int r0 = (gp ? 2*HD : 0) + h;        // i-row or g-row
        const int r1 = (gp ? 3*HD : HD) + h;       // f-row or o-row
        #pragma unroll
        for (int j = 0; j < 9; ++j) {
            W0[j]   = v2h{(_Float16)wih[r0*HD + 2*j], (_Float16)wih[r0*HD + 2*j+1]};
            W0[9+j] = v2h{(_Float16)whh[r0*HD + 2*j], (_Float16)whh[r0*HD + 2*j+1]};
            W1[j]   = v2h{(_Float16)wih[r1*HD + 2*j], (_Float16)wih[r1*HD + 2*j+1]};
            W1[9+j] = v2h{(_Float16)whh[r1*HD + 2*j], (_Float16)whh[r1*HD + 2*j+1]};
        }
        bias0 = bi[r0] + bh[r0];
        bias1 = bi[r1] + bh[r1];
    }

    const float* xb = x   + gb*TT*HD;
    float*       ob = out + gb*TT*HD;

    // ---- init LDS state ----
    if (act) {
        if (!role2) {
            _Float16* f = (_Float16*)&in1[0][b][0];
            if (gp) f[h]      = (_Float16)xb[h];   // x[0]
            else    f[HD + h] = (_Float16)0.f;     // h1[-1]
        } else if (!gp) {
            ((_Float16*)&in2[1][b][0])[HD + h] = (_Float16)0.f;  // h2[-1]
        }
    }
    __syncthreads();

    float c = 0.f;

    for (int n = 0; n <= TT; ++n) {
        const int  p   = n & 1;
        const bool run = act && (role2 ? (n >= 1) : (n < TT));

        // prefetch next x element (layer-1 gp1 lanes stage x)
        float xn = 0.f;
        if (!role2 && act && gp && (n + 1) < TT) xn = xb[(size_t)(n + 1)*HD + h];

        if (run) {
            const uint* rp = role2 ? &in2[p][b][0] : &in1[p][b][0];
            float a0 = bias0, a1 = bias1;
            #pragma unroll
            for (int j = 0; j < 18; ++j) {
                const uint w = rp[j];
                const v2h  v = __builtin_bit_cast(v2h, w);
                a0 = __builtin_amdgcn_fdot2(v, W0[j], a0, false);
                a1 = __builtin_amdgcn_fdot2(v, W1[j], a1, false);
            }
            // own gates: gp0 -> (i,f) ; gp1 -> (g,o)  [tanh via 2*sig(2x)-1]
            const float s0 = fsig(gp ? 2.f*a0 : a0);
            const float u0 = gp ? 2.f*s0 - 1.f : s0;
            const float u1 = fsig(a1);
            const float v0 = __shfl_xor(u0, 1, 64);
            const float v1 = __shfl_xor(u1, 1, 64);
            const float gi = gp ? v0 : u0;
            const float gf = gp ? v1 : u1;
            const float gg = gp ? u0 : v0;
            const float go = gp ? u1 : v1;
            c = gf * c + gi * gg;
            const float th = 2.f * fsig(2.f*c) - 1.f;
            const float hv = go * th;
            const _Float16 hv16 = (_Float16)hv;

            if (!role2) {
                if (!gp) ((_Float16*)&in1[p^1][b][0])[HD + h] = hv16;  // h1 -> own next
                else {
                    ((_Float16*)&in2[p^1][b][0])[h] = hv16;            // h1 -> layer2
                    if ((n + 1) < TT) ((_Float16*)&in1[p^1][b][0])[h] = (_Float16)xn;
                }
            } else {
                if (!gp) ((_Float16*)&in2[p^1][b][0])[HD + h] = hv16;  // h2 -> own next
                else     ob[(size_t)(n - 1)*HD + h] = hv;              // output h2[n-1]
            }
        }
        __syncthreads();
    }
}

extern "C" void kernel_launch(void* const* d_in, const int* in_sizes, int n_in,
                              void* d_out, int out_size, void* d_ws, size_t ws_size,
                              hipStream_t stream) {
    const float* x    = (const float*)d_in[0];
    const float* wih0 = (const float*)d_in[1];
    const float* whh0 = (const float*)d_in[2];
    const float* bih0 = (const float*)d_in[3];
    const float* bhh0 = (const float*)d_in[4];
    const float* wih1 = (const float*)d_in[5];
    const float* whh1 = (const float*)d_in[6];
    const float* bih1 = (const float*)d_in[7];
    const float* bhh1 = (const float*)d_in[8];
    float* out = (float*)d_out;

    lstm2_dot<<<dim3(4096 / CH), dim3(NTH), 0, stream>>>(
        x, wih0, whh0, bih0, bhh0, wih1, whh1, bih1, bhh1, out);
}